// Round 2
// baseline (2651.516 us; speedup 1.0000x reference)
//
#include <hip/hip_runtime.h>
#include <hip/hip_bf16.h>
#include <math.h>

#define Bdim 16
#define Mdim 4096
#define Tdim 4
#define Ddim 256
#define Vdim 40000
#define CONVMAX 512

#define RD_ROWS 64
#define K1_BLOCKS (Vdim / RD_ROWS)            // 625 (exact)
#define K3_ROWS 128
#define K3_BLOCKS ((Vdim + K3_ROWS - 1) / K3_ROWS)  // 313

// ---------------------------------------------------------------------------
// embed3: out_m[b,m,:] = sum_t C3[story[b,m,t],:] (+ history window)
// grid B*M/4 blocks x 256 (wave per m)
// ---------------------------------------------------------------------------
__global__ __launch_bounds__(256) void embed3_kernel(
    const int* __restrict__ story, const int* __restrict__ kb_len,
    const int* __restrict__ conv_len, const float* __restrict__ hist,
    const float* __restrict__ tab, float* __restrict__ outm) {
    int bid = blockIdx.x;
    int b   = bid / (Mdim / 4);
    int mc  = bid % (Mdim / 4);
    int tid = threadIdx.x;
    int m   = mc * 4 + (tid >> 6);
    int lane = tid & 63;
    int d4  = lane * 4;

    const int* st = story + ((size_t)b * Mdim + m) * Tdim;
    float4 acc = make_float4(0.f, 0.f, 0.f, 0.f);
#pragma unroll
    for (int t = 0; t < Tdim; ++t) {
        const float4 v = *(const float4*)(tab + (size_t)st[t] * Ddim + d4);
        acc.x += v.x; acc.y += v.y; acc.z += v.z; acc.w += v.w;
    }
    int kb = kb_len[b], cl = conv_len[b];
    if (m >= kb && m < kb + cl) {
        const float4 h = *(const float4*)(hist + ((size_t)b * CONVMAX + (m - kb)) * Ddim + d4);
        acc.x += h.x; acc.y += h.y; acc.z += h.z; acc.w += h.w;
    }
    *(float4*)(outm + ((size_t)b * Mdim + m) * Ddim + d4) = acc;
}

// ---------------------------------------------------------------------------
// K1: rowdot rd[b][v] = C[v]·u[b]  (blocks 0..624, 64 rows each, reg-tiled)
//     + hw[b][j] = hist[b][j]·u[b] (blocks 625..640)
//     + zero wsum (rowdot blocks) and o_part (hw blocks)
// ---------------------------------------------------------------------------
__global__ __launch_bounds__(256) void rowdot_kernel(
    const float* __restrict__ table, const float* __restrict__ u,
    const float* __restrict__ histin, float* __restrict__ rd,
    float* __restrict__ hw, float* __restrict__ wsum, float* __restrict__ o_part) {
    int bid = blockIdx.x, tid = threadIdx.x;
    __shared__ float Cl[RD_ROWS * 68];   // 64 x 64, stride 68
    __shared__ float Ut[Ddim * 20];      // [d][b], stride 20 (16B aligned)

    if (bid >= K1_BLOCKS) {
        int b = bid - K1_BLOCKS;                       // 0..15
        float4 z = make_float4(0.f, 0.f, 0.f, 0.f);
        ((float4*)o_part)[b * 256 + tid];              // no-op read avoided below
        ((float4*)o_part)[b * 256 + tid] = z;          // 4*B*D floats = 16 * 1024 f4
        int wid = tid >> 6, lane = tid & 63;
        const float4 uv = ((const float4*)(u + (size_t)b * Ddim))[lane];
        for (int j = wid; j < CONVMAX; j += 4) {
            const float4 h = ((const float4*)(histin + ((size_t)b * CONVMAX + j) * Ddim))[lane];
            float s = h.x * uv.x + h.y * uv.y + h.z * uv.z + h.w * uv.w;
#pragma unroll
            for (int off = 32; off > 0; off >>= 1) s += __shfl_xor(s, off, 64);
            if (lane == 0) hw[b * CONVMAX + j] = s;
        }
        return;
    }

    // zero wsum slice: 640000 floats / 625 blocks = 1024 floats
    ((float4*)wsum)[bid * 256 + tid] = make_float4(0.f, 0.f, 0.f, 0.f);

    // stage u transposed: Ut[d*20 + b]
    for (int i = tid; i < Bdim * Ddim; i += 256) {
        int b = i >> 8, d = i & 255;
        Ut[d * 20 + b] = u[i];
    }
    __syncthreads();

    int v0 = bid * RD_ROWS;
    int v_loc = tid >> 2, bq = tid & 3;
    float acc0 = 0.f, acc1 = 0.f, acc2 = 0.f, acc3 = 0.f;
#pragma unroll
    for (int dc = 0; dc < 4; ++dc) {
#pragma unroll
        for (int i = 0; i < 4; ++i) {
            int flat = tid + i * 256;
            int row = flat >> 4, c4 = flat & 15;
            float4 v = *(const float4*)(table + (size_t)(v0 + row) * Ddim + dc * 64 + c4 * 4);
            *(float4*)(Cl + row * 68 + c4 * 4) = v;
        }
        __syncthreads();
#pragma unroll 8
        for (int d = 0; d < 64; ++d) {
            float c = Cl[v_loc * 68 + d];
            float4 uu = *(const float4*)(Ut + (dc * 64 + d) * 20 + bq * 4);
            acc0 += c * uu.x; acc1 += c * uu.y; acc2 += c * uu.z; acc3 += c * uu.w;
        }
        __syncthreads();
    }
    rd[(size_t)(bq * 4 + 0) * Vdim + v0 + v_loc] = acc0;
    rd[(size_t)(bq * 4 + 1) * Vdim + v0 + v_loc] = acc1;
    rd[(size_t)(bq * 4 + 2) * Vdim + v0 + v_loc] = acc2;
    rd[(size_t)(bq * 4 + 3) * Vdim + v0 + v_loc] = acc3;
}

// ---------------------------------------------------------------------------
// K2 (fat, grid=B, 1024 thr): assemble logits (rd gather + window), softmax,
// scatter prob into wsum histogram, window-o into o_part[0]; outputs.
// ---------------------------------------------------------------------------
__global__ __launch_bounds__(1024) void pass_mid_kernel(
    const int* __restrict__ story, const int* __restrict__ kb_len,
    const int* __restrict__ conv_len, const float* __restrict__ rd,
    const float* __restrict__ hw, const float* __restrict__ gp,
    const float* __restrict__ histin, float* __restrict__ wsum,
    float* __restrict__ o_part, float* __restrict__ out_logits,
    float* __restrict__ out_psoft) {
    int b = blockIdx.x, tid = threadIdx.x;
    __shared__ float lg[Mdim];
    __shared__ float red[32];
    __shared__ float o_lds[Ddim];
    int kb = kb_len[b], cl = conv_len[b];
    const float* rdb = rd + (size_t)b * Vdim;

    int4 st[4];
    float raw[4], gv[4];
    float lmax = -INFINITY;
#pragma unroll
    for (int k = 0; k < 4; ++k) {
        int m = tid + k * 1024;
        st[k] = *(const int4*)(story + ((size_t)b * Mdim + m) * Tdim);
        float s = rdb[st[k].x] + rdb[st[k].y] + rdb[st[k].z] + rdb[st[k].w];
        int j = m - kb;
        if (j >= 0 && j < cl) s += hw[b * CONVMAX + j];
        gv[k] = 1.f;
        if (gp) { gv[k] = gp[(size_t)b * Mdim + m]; s *= gv[k]; }
        if (out_logits) out_logits[(size_t)b * Mdim + m] = s;
        raw[k] = s;
        lmax = fmaxf(lmax, s);
    }
    // block max
#pragma unroll
    for (int off = 32; off > 0; off >>= 1) lmax = fmaxf(lmax, __shfl_xor(lmax, off, 64));
    if ((tid & 63) == 0) red[tid >> 6] = lmax;
    __syncthreads();
    if (tid < 16) {
        float v = red[tid];
#pragma unroll
        for (int off = 8; off > 0; off >>= 1) v = fmaxf(v, __shfl_xor(v, off, 64));
        if (tid == 0) red[16] = v;
    }
    __syncthreads();
    float bmax = red[16];

    float e[4], lsum = 0.f;
#pragma unroll
    for (int k = 0; k < 4; ++k) {
        int m = tid + k * 1024;
        e[k] = expf(raw[k] - bmax);
        lg[m] = e[k];
        lsum += e[k];
    }
#pragma unroll
    for (int off = 32; off > 0; off >>= 1) lsum += __shfl_xor(lsum, off, 64);
    if ((tid & 63) == 0) red[tid >> 6] = lsum;
    __syncthreads();
    if (tid < 16) {
        float v = red[tid];
#pragma unroll
        for (int off = 8; off > 0; off >>= 1) v += __shfl_xor(v, off, 64);
        if (tid == 0) red[17] = 1.0f / v;
    }
    __syncthreads();
    float rs = red[17];

    // scatter into histogram
#pragma unroll
    for (int k = 0; k < 4; ++k) {
        int m = tid + k * 1024;
        float p = e[k] * rs;
        if (out_psoft) out_psoft[(size_t)b * Mdim + m] = p;
        float w = p * gv[k];
        atomicAdd(&wsum[(size_t)b * Vdim + st[k].x], w);
        atomicAdd(&wsum[(size_t)b * Vdim + st[k].y], w);
        atomicAdd(&wsum[(size_t)b * Vdim + st[k].z], w);
        atomicAdd(&wsum[(size_t)b * Vdim + st[k].w], w);
    }

    // window-o: o += sum_j p[kb+j]*gp*hist[b][j]
    if (tid < 256) o_lds[tid] = 0.f;
    __syncthreads();
    int j0 = tid >> 6, d4 = tid & 63;
    float4 acc = make_float4(0.f, 0.f, 0.f, 0.f);
    for (int j = j0; j < cl; j += 16) {
        float w = lg[kb + j] * rs;
        if (gp) w *= gp[(size_t)b * Mdim + kb + j];
        const float4 h = *(const float4*)(histin + ((size_t)b * CONVMAX + j) * Ddim + d4 * 4);
        acc.x += w * h.x; acc.y += w * h.y; acc.z += w * h.z; acc.w += w * h.w;
    }
    atomicAdd(&o_lds[d4 * 4 + 0], acc.x);
    atomicAdd(&o_lds[d4 * 4 + 1], acc.y);
    atomicAdd(&o_lds[d4 * 4 + 2], acc.z);
    atomicAdd(&o_lds[d4 * 4 + 3], acc.w);
    __syncthreads();
    if (tid < 256) o_part[b * Ddim + tid] = o_lds[tid];  // copy 0 (zeroed in K1)
}

// ---------------------------------------------------------------------------
// K3: o[b] += sum_v wsum[b][v] * C2[v]  — table swept once, 128 rows/block
// ---------------------------------------------------------------------------
__global__ __launch_bounds__(256) void wsum_sweep_kernel(
    const float* __restrict__ table2, const float* __restrict__ wsum,
    float* __restrict__ o_part) {
    __shared__ float Wl[K3_ROWS * 20];   // [r][b], stride 20
    __shared__ float Of[Bdim * Ddim];    // 16 KB fold buffer
    int bid = blockIdx.x, tid = threadIdx.x;
    int v0 = bid * K3_ROWS;

    for (int i = tid; i < Bdim * K3_ROWS; i += 256) {
        int b = i >> 7, r = i & 127;
        float w = (v0 + r < Vdim) ? wsum[(size_t)b * Vdim + v0 + r] : 0.f;
        Wl[r * 20 + b] = w;
    }
    for (int i = tid; i < Bdim * Ddim; i += 256) Of[i] = 0.f;
    __syncthreads();

    int wid = tid >> 6, lane = tid & 63;
    float4 acc[16];
#pragma unroll
    for (int i = 0; i < 16; ++i) acc[i] = make_float4(0.f, 0.f, 0.f, 0.f);

    for (int r = wid; r < K3_ROWS; r += 4) {
        if (v0 + r >= Vdim) break;
        const float4 cv = *(const float4*)(table2 + (size_t)(v0 + r) * Ddim + lane * 4);
#pragma unroll
        for (int bq = 0; bq < 4; ++bq) {
            float4 w4 = *(const float4*)(Wl + r * 20 + bq * 4);
            acc[bq * 4 + 0].x += cv.x * w4.x; acc[bq * 4 + 0].y += cv.y * w4.x;
            acc[bq * 4 + 0].z += cv.z * w4.x; acc[bq * 4 + 0].w += cv.w * w4.x;
            acc[bq * 4 + 1].x += cv.x * w4.y; acc[bq * 4 + 1].y += cv.y * w4.y;
            acc[bq * 4 + 1].z += cv.z * w4.y; acc[bq * 4 + 1].w += cv.w * w4.y;
            acc[bq * 4 + 2].x += cv.x * w4.z; acc[bq * 4 + 2].y += cv.y * w4.z;
            acc[bq * 4 + 2].z += cv.z * w4.z; acc[bq * 4 + 2].w += cv.w * w4.z;
            acc[bq * 4 + 3].x += cv.x * w4.w; acc[bq * 4 + 3].y += cv.y * w4.w;
            acc[bq * 4 + 3].z += cv.z * w4.w; acc[bq * 4 + 3].w += cv.w * w4.w;
        }
    }
#pragma unroll
    for (int bb = 0; bb < 16; ++bb) {
        atomicAdd(&Of[bb * Ddim + lane * 4 + 0], acc[bb].x);
        atomicAdd(&Of[bb * Ddim + lane * 4 + 1], acc[bb].y);
        atomicAdd(&Of[bb * Ddim + lane * 4 + 2], acc[bb].z);
        atomicAdd(&Of[bb * Ddim + lane * 4 + 3], acc[bb].w);
    }
    __syncthreads();
    float* op = o_part + (size_t)(bid & 3) * Bdim * Ddim;
    for (int i = tid; i < Bdim * Ddim; i += 256) atomicAdd(&op[i], Of[i]);
}

// ---------------------------------------------------------------------------
// K4: u_out = u_in + sum(o_part), optional gate (Tg matvec)
// ---------------------------------------------------------------------------
__global__ __launch_bounds__(256) void update_kernel(
    const float* __restrict__ u_in, const float* __restrict__ o_part, int use_gate,
    const float* __restrict__ W, const float* __restrict__ bias,
    const float* __restrict__ prevu, float* __restrict__ u_out) {
    int b = blockIdx.x, i = threadIdx.x;
    __shared__ float sh[Ddim];
    float o = o_part[b * Ddim + i] + o_part[(Bdim + b) * Ddim + i] +
              o_part[(2 * Bdim + b) * Ddim + i] + o_part[(3 * Bdim + b) * Ddim + i];
    float uk = u_in[(size_t)b * Ddim + i] + o;
    if (!use_gate) { u_out[(size_t)b * Ddim + i] = uk; return; }
    sh[i] = uk; __syncthreads();
    float s = bias[i];
    const float4* Wr = (const float4*)(W + (size_t)i * Ddim);
    const float4* sh4 = (const float4*)sh;
    for (int j = 0; j < 64; ++j) {
        float4 w = Wr[j], x = sh4[j];
        s += w.x * x.x + w.y * x.y + w.z * x.z + w.w * x.w;
    }
    float g = 1.0f / (1.0f + expf(-s));
    u_out[(size_t)b * Ddim + i] = prevu[(size_t)b * Ddim + i] * g + uk * (1.0f - g);
}

// ---------------------------------------------------------------------------
// start: layer0: u0 = query; else: q = relu(FW·prev_u3+b); gate with Tg[0]
// ---------------------------------------------------------------------------
__global__ __launch_bounds__(256) void start_kernel(
    int layer0, const float* __restrict__ query, const float* __restrict__ FW_w,
    const float* __restrict__ FW_b, const float* __restrict__ Tg_w,
    const float* __restrict__ Tg_b, const float* __restrict__ prev_u,
    float* __restrict__ u0_out) {
    int b = blockIdx.x, i = threadIdx.x;
    __shared__ float sh[Ddim];
    __shared__ float qsh[Ddim];
    if (layer0) { u0_out[(size_t)b * Ddim + i] = query[(size_t)b * Ddim + i]; return; }
    sh[i] = prev_u[(size_t)3 * Bdim * Ddim + b * Ddim + i];
    __syncthreads();
    float s = FW_b[i];
    {
        const float4* Wr = (const float4*)(FW_w + (size_t)i * Ddim);
        const float4* sh4 = (const float4*)sh;
        for (int j = 0; j < 64; ++j) {
            float4 w = Wr[j], x = sh4[j];
            s += w.x * x.x + w.y * x.y + w.z * x.z + w.w * x.w;
        }
    }
    float q = fmaxf(s, 0.f);
    qsh[i] = q;
    __syncthreads();
    float t = Tg_b[i];
    {
        const float4* Wr = (const float4*)(Tg_w + (size_t)i * Ddim);
        const float4* sh4 = (const float4*)qsh;
        for (int j = 0; j < 64; ++j) {
            float4 w = Wr[j], x = sh4[j];
            t += w.x * x.x + w.y * x.y + w.z * x.z + w.w * x.w;
        }
    }
    float g = 1.0f / (1.0f + expf(-t));
    u0_out[(size_t)b * Ddim + i] = prev_u[(size_t)b * Ddim + i] * g + q * (1.0f - g);
}

extern "C" void kernel_launch(void* const* d_in, const int* in_sizes, int n_in,
                              void* d_out, int out_size, void* d_ws, size_t ws_size,
                              hipStream_t stream) {
    const int*   story        = (const int*)d_in[0];
    const int*   kb_len       = (const int*)d_in[1];
    const int*   conv_len     = (const int*)d_in[2];
    const float* query        = (const float*)d_in[3];
    const float* hist         = (const float*)d_in[4];
    const float* query_vector = (const float*)d_in[5];
    const float* gp           = (const float*)d_in[6];
    const float* C_emb        = (const float*)d_in[7];
    const float* Tg_w         = (const float*)d_in[8];
    const float* Tg_b         = (const float*)d_in[9];
    const float* FW_w         = (const float*)d_in[10];
    const float* FW_b         = (const float*)d_in[11];

    float* out        = (float*)d_out;
    float* out_psoft  = out;
    float* out_logits = out + (size_t)Bdim * Mdim;
    float* out_uf     = out + 2 * (size_t)Bdim * Mdim;
    float* out_m      = out + 2 * (size_t)Bdim * Mdim + (size_t)Bdim * Ddim;

    const size_t BV = (size_t)Bdim * Vdim;
    const size_t BD = (size_t)Bdim * Ddim;
    const size_t VD = (size_t)Vdim * Ddim;
    float* ws     = (float*)d_ws;
    float* rd     = ws;                 // B*V
    float* wsum   = rd + BV;            // B*V
    float* hw     = wsum + BV;          // B*512
    float* o_part = hw + (size_t)Bdim * CONVMAX;  // 4*B*D
    float* uA     = o_part + 4 * BD;    // 4*B*D
    float* uB     = uA + 4 * BD;        // 4*B*D

    embed3_kernel<<<Bdim * (Mdim / 4), 256, 0, stream>>>(
        story, kb_len, conv_len, hist, C_emb + 3 * VD, out_m);

    float* cur = uA;
    float* prev = uB;
    for (int layer = 0; layer < 3; ++layer) {
        start_kernel<<<Bdim, Ddim, 0, stream>>>(
            layer == 0 ? 1 : 0, query, FW_w, FW_b, Tg_w, Tg_b, prev, cur);
        for (int hop = 0; hop < 3; ++hop) {
            const float* u = cur + (size_t)hop * BD;
            rowdot_kernel<<<K1_BLOCKS + Bdim, 256, 0, stream>>>(
                C_emb + (size_t)hop * VD, u, hist, rd, hw, wsum, o_part);
            pass_mid_kernel<<<Bdim, 1024, 0, stream>>>(
                story, kb_len, conv_len, rd, hw, nullptr, hist, wsum, o_part,
                nullptr, nullptr);
            wsum_sweep_kernel<<<K3_BLOCKS, 256, 0, stream>>>(
                C_emb + (size_t)(hop + 1) * VD, wsum, o_part);
            update_kernel<<<Bdim, Ddim, 0, stream>>>(
                u, o_part, layer > 0 ? 1 : 0,
                Tg_w + (size_t)(hop + 1) * Ddim * Ddim, Tg_b + (size_t)(hop + 1) * Ddim,
                prev + (size_t)(hop + 1) * BD, cur + (size_t)(hop + 1) * BD);
        }
        float* tmp = cur; cur = prev; prev = tmp;
    }

    // final global-pointer stage (uf chain lives in out_uf)
    for (int h = 0; h < 3; ++h) {
        const float* uf = (h == 0) ? query_vector : out_uf;
        rowdot_kernel<<<K1_BLOCKS + Bdim, 256, 0, stream>>>(
            C_emb + (size_t)h * VD, uf, hist, rd, hw, wsum, o_part);
        pass_mid_kernel<<<Bdim, 1024, 0, stream>>>(
            story, kb_len, conv_len, rd, hw, gp, hist, wsum, o_part,
            (h == 2) ? out_logits : nullptr, (h == 2) ? out_psoft : nullptr);
        wsum_sweep_kernel<<<K3_BLOCKS, 256, 0, stream>>>(
            C_emb + (size_t)(h + 1) * VD, wsum, o_part);
        update_kernel<<<Bdim, Ddim, 0, stream>>>(
            uf, o_part, 0, nullptr, nullptr, nullptr, out_uf);
    }
}

// Round 3
// 2344.991 us; speedup vs baseline: 1.1307x; 1.1307x over previous
//
#include <hip/hip_runtime.h>
#include <hip/hip_bf16.h>
#include <math.h>

#define Bdim 16
#define Mdim 4096
#define Ddim 256
#define Vdim 40000
#define CONVMAX 512
#define NVBLK 625            // 40000 / 64

// ---------------------------------------------------------------------------
// embed3: out_m[b,m,:] = sum_t C3[story[b,m,t],:] (+ history window)
// ---------------------------------------------------------------------------
__global__ __launch_bounds__(256) void embed3_kernel(
    const int* __restrict__ story, const int* __restrict__ kb_len,
    const int* __restrict__ conv_len, const float* __restrict__ hist,
    const float* __restrict__ tab, float* __restrict__ outm) {
    int bid = blockIdx.x;
    int b   = bid / (Mdim / 4);
    int mc  = bid % (Mdim / 4);
    int tid = threadIdx.x;
    int m   = mc * 4 + (tid >> 6);
    int lane = tid & 63;
    int d4  = lane * 4;

    const int* st = story + ((size_t)b * Mdim + m) * 4;
    float4 acc = make_float4(0.f, 0.f, 0.f, 0.f);
#pragma unroll
    for (int t = 0; t < 4; ++t) {
        const float4 v = *(const float4*)(tab + (size_t)st[t] * Ddim + d4);
        acc.x += v.x; acc.y += v.y; acc.z += v.z; acc.w += v.w;
    }
    int kb = kb_len[b], cl = conv_len[b];
    if (m >= kb && m < kb + cl) {
        const float4 h = *(const float4*)(hist + ((size_t)b * CONVMAX + (m - kb)) * Ddim + d4);
        acc.x += h.x; acc.y += h.y; acc.z += h.z; acc.w += h.w;
    }
    *(float4*)(outm + ((size_t)b * Mdim + m) * Ddim + d4) = acc;
}

// ---------------------------------------------------------------------------
// K1: rd[v][b] = C[v]·u[b] for all 16 b (blocks 0..624, 64 rows each)
//     + hw[b][j] = hist[b][j]·u[b] (blocks 625..688) + zero wsum / o_win
// thread: q=t&3 (d-quarter), bq=(t>>2)&3 (b-quad), r4=t>>4 (4 rows)
// u staged in LDS with permuted rows rho(d)=((d&63)<<2)|(d>>6) to kill
// the q-lane bank aliasing (q-lanes differ by d+=64 which is bank-invariant
// under any linear stride; permutation makes q the low bits).
// ---------------------------------------------------------------------------
__global__ __launch_bounds__(256) void rowdot_kernel(
    const float* __restrict__ table, const float* __restrict__ u,
    const float* __restrict__ histin, float* __restrict__ rd,
    float* __restrict__ hw, float* __restrict__ wsum, float* __restrict__ o_win) {
    int bid = blockIdx.x, t = threadIdx.x;

    if (bid >= NVBLK) {
        int xb = bid - NVBLK;           // 0..63
        int b = xb >> 2, jq = xb & 3;
        if (jq == 0) o_win[b * Ddim + t] = 0.f;
        int wid = t >> 6, lane = t & 63;
        const float4 uv = ((const float4*)(u + b * Ddim))[lane];
#pragma unroll 4
        for (int rep = 0; rep < 32; ++rep) {
            int j = jq * 128 + wid * 32 + rep;
            const float4 h = ((const float4*)(histin + ((size_t)b * CONVMAX + j) * Ddim))[lane];
            float s = h.x * uv.x + h.y * uv.y + h.z * uv.z + h.w * uv.w;
#pragma unroll
            for (int off = 32; off > 0; off >>= 1) s += __shfl_xor(s, off, 64);
            if (lane == 0) hw[b * CONVMAX + j] = s;
        }
        return;
    }

    int v0 = bid * 64;
    // zero this block's wsum slice (16 b x 64 v)
    {
        int zb = t >> 4, vo = (t & 15) * 4;
        *(float4*)(wsum + (size_t)zb * Vdim + v0 + vo) = make_float4(0.f, 0.f, 0.f, 0.f);
    }

    __shared__ float Ut[4096];          // [rho][b], rho = ((d&63)<<2)|(d>>6)
    for (int i = t; i < 4096; i += 256) {
        int b = i & 15, d = i >> 4;
        int rho = ((d & 63) << 2) | (d >> 6);
        Ut[rho * 16 + b] = u[b * Ddim + d];
    }
    __syncthreads();

    int q = t & 3, bq = (t >> 2) & 3, r4 = t >> 4;
    int vbase = v0 + r4 * 4;
    const float* rp0 = table + (size_t)(vbase + 0) * Ddim + q * 64;
    const float* rp1 = table + (size_t)(vbase + 1) * Ddim + q * 64;
    const float* rp2 = table + (size_t)(vbase + 2) * Ddim + q * 64;
    const float* rp3 = table + (size_t)(vbase + 3) * Ddim + q * 64;
    const float* ub = Ut + 16 * q + 4 * bq;

    float4 a0 = make_float4(0.f,0.f,0.f,0.f), a1 = a0, a2 = a0, a3 = a0;
#pragma unroll 2
    for (int k = 0; k < 16; ++k) {
        float4 c0 = ((const float4*)rp0)[k];
        float4 c1 = ((const float4*)rp1)[k];
        float4 c2 = ((const float4*)rp2)[k];
        float4 c3 = ((const float4*)rp3)[k];
        float4 ua = *(const float4*)(ub + 256 * k + 0);
        float4 ux = *(const float4*)(ub + 256 * k + 64);
        float4 uc = *(const float4*)(ub + 256 * k + 128);
        float4 ud = *(const float4*)(ub + 256 * k + 192);
        a0.x += c0.x*ua.x + c0.y*ux.x + c0.z*uc.x + c0.w*ud.x;
        a0.y += c0.x*ua.y + c0.y*ux.y + c0.z*uc.y + c0.w*ud.y;
        a0.z += c0.x*ua.z + c0.y*ux.z + c0.z*uc.z + c0.w*ud.z;
        a0.w += c0.x*ua.w + c0.y*ux.w + c0.z*uc.w + c0.w*ud.w;
        a1.x += c1.x*ua.x + c1.y*ux.x + c1.z*uc.x + c1.w*ud.x;
        a1.y += c1.x*ua.y + c1.y*ux.y + c1.z*uc.y + c1.w*ud.y;
        a1.z += c1.x*ua.z + c1.y*ux.z + c1.z*uc.z + c1.w*ud.z;
        a1.w += c1.x*ua.w + c1.y*ux.w + c1.z*uc.w + c1.w*ud.w;
        a2.x += c2.x*ua.x + c2.y*ux.x + c2.z*uc.x + c2.w*ud.x;
        a2.y += c2.x*ua.y + c2.y*ux.y + c2.z*uc.y + c2.w*ud.y;
        a2.z += c2.x*ua.z + c2.y*ux.z + c2.z*uc.z + c2.w*ud.z;
        a2.w += c2.x*ua.w + c2.y*ux.w + c2.z*uc.w + c2.w*ud.w;
        a3.x += c3.x*ua.x + c3.y*ux.x + c3.z*uc.x + c3.w*ud.x;
        a3.y += c3.x*ua.y + c3.y*ux.y + c3.z*uc.y + c3.w*ud.y;
        a3.z += c3.x*ua.z + c3.y*ux.z + c3.z*uc.z + c3.w*ud.z;
        a3.w += c3.x*ua.w + c3.y*ux.w + c3.z*uc.w + c3.w*ud.w;
    }
    // reduce over q (lane bits 0..1), elementwise on all 16 accs
#pragma unroll
    for (int st = 1; st <= 2; st <<= 1) {
        a0.x += __shfl_xor(a0.x, st, 64); a0.y += __shfl_xor(a0.y, st, 64);
        a0.z += __shfl_xor(a0.z, st, 64); a0.w += __shfl_xor(a0.w, st, 64);
        a1.x += __shfl_xor(a1.x, st, 64); a1.y += __shfl_xor(a1.y, st, 64);
        a1.z += __shfl_xor(a1.z, st, 64); a1.w += __shfl_xor(a1.w, st, 64);
        a2.x += __shfl_xor(a2.x, st, 64); a2.y += __shfl_xor(a2.y, st, 64);
        a2.z += __shfl_xor(a2.z, st, 64); a2.w += __shfl_xor(a2.w, st, 64);
        a3.x += __shfl_xor(a3.x, st, 64); a3.y += __shfl_xor(a3.y, st, 64);
        a3.z += __shfl_xor(a3.z, st, 64); a3.w += __shfl_xor(a3.w, st, 64);
    }
    // lane's q picks which of its 4 rows to store (all q hold full sums)
    float4 w = (q == 0) ? a0 : (q == 1) ? a1 : (q == 2) ? a2 : a3;
    *(float4*)(rd + (size_t)(vbase + q) * Bdim + bq * 4) = w;
}

// ---------------------------------------------------------------------------
// K2a: logits[b][m] = gather(rd) + window (+ *gp); per-chunk (max, sumexp)
// grid 256 = 16 b x 16 chunks of 256 m
// ---------------------------------------------------------------------------
__global__ __launch_bounds__(256) void logit_kernel(
    const int* __restrict__ story, const int* __restrict__ kb_len,
    const int* __restrict__ conv_len, const float* __restrict__ rd,
    const float* __restrict__ hw, const float* __restrict__ gp,
    float* __restrict__ logits, float* __restrict__ pmax, float* __restrict__ psum) {
    int bid = blockIdx.x, t = threadIdx.x;
    int b = bid >> 4, m = ((bid & 15) << 8) + t;
    const int4 st = *(const int4*)(story + ((size_t)b * Mdim + m) * 4);
    float s = rd[(size_t)st.x * Bdim + b] + rd[(size_t)st.y * Bdim + b] +
              rd[(size_t)st.z * Bdim + b] + rd[(size_t)st.w * Bdim + b];
    int kb = kb_len[b], cl = conv_len[b];
    int j = m - kb;
    if (j >= 0 && j < cl) s += hw[b * CONVMAX + j];
    if (gp) s *= gp[(size_t)b * Mdim + m];
    logits[(size_t)b * Mdim + m] = s;

    __shared__ float sh[256];
    float v = s;
#pragma unroll
    for (int off = 32; off > 0; off >>= 1) v = fmaxf(v, __shfl_xor(v, off, 64));
    if ((t & 63) == 0) sh[t >> 6] = v;
    __syncthreads();
    float bm = fmaxf(fmaxf(sh[0], sh[1]), fmaxf(sh[2], sh[3]));
    __syncthreads();
    float e = expf(s - bm);
#pragma unroll
    for (int off = 32; off > 0; off >>= 1) e += __shfl_xor(e, off, 64);
    if ((t & 63) == 0) sh[t >> 6] = e;
    __syncthreads();
    if (t == 0) {
        pmax[bid] = bm;
        psum[bid] = sh[0] + sh[1] + sh[2] + sh[3];
    }
}

// ---------------------------------------------------------------------------
// K2c: combine chunk partials -> softmax; scatter w into wsum histogram;
// window-o fold into o_win; optional psoft output.  grid 256 as K2a.
// ---------------------------------------------------------------------------
__global__ __launch_bounds__(256) void scatter_kernel(
    const int* __restrict__ story, const int* __restrict__ kb_len,
    const int* __restrict__ conv_len, const float* __restrict__ logits,
    const float* __restrict__ pmax, const float* __restrict__ psum,
    const float* __restrict__ gp, const float* __restrict__ histin,
    float* __restrict__ wsum, float* __restrict__ o_win,
    float* __restrict__ out_psoft) {
    int bid = blockIdx.x, t = threadIdx.x;
    int b = bid >> 4, m0 = (bid & 15) << 8, m = m0 + t;

    float bmax = -INFINITY;
#pragma unroll
    for (int c = 0; c < 16; ++c) bmax = fmaxf(bmax, pmax[b * 16 + c]);
    float S = 0.f;
#pragma unroll
    for (int c = 0; c < 16; ++c) S += psum[b * 16 + c] * expf(pmax[b * 16 + c] - bmax);
    float rs = 1.0f / S;

    float lg = logits[(size_t)b * Mdim + m];
    float p = expf(lg - bmax) * rs;
    if (out_psoft) out_psoft[(size_t)b * Mdim + m] = p;
    float w = p;
    if (gp) w *= gp[(size_t)b * Mdim + m];

    const int4 st = *(const int4*)(story + ((size_t)b * Mdim + m) * 4);
    atomicAdd(&wsum[(size_t)b * Vdim + st.x], w);
    atomicAdd(&wsum[(size_t)b * Vdim + st.y], w);
    atomicAdd(&wsum[(size_t)b * Vdim + st.z], w);
    atomicAdd(&wsum[(size_t)b * Vdim + st.w], w);

    __shared__ float pl[256];
    pl[t] = w;
    __syncthreads();
    int kb = kb_len[b], cl = conv_len[b];
    int r0 = kb - m0; if (r0 < 0) r0 = 0;
    int r1 = kb + cl - m0; if (r1 > 256) r1 = 256;
    if (r1 > r0) {
        float a = 0.f;
        for (int r = r0; r < r1; ++r)
            a += pl[r] * histin[((size_t)b * CONVMAX + (m0 + r - kb)) * Ddim + t];
        atomicAdd(&o_win[b * Ddim + t], a);
    }
}

// ---------------------------------------------------------------------------
// K3: per-block partial o_str[bid][b][d] = sum_{v in tile} wsum[b][v]*C2[v][d]
// thread: d4 = t&63 (float4 of d), bh = t>>6 (4 b's). Coalesced 1KB row loads.
// ---------------------------------------------------------------------------
__global__ __launch_bounds__(256) void wsum_sweep_kernel(
    const float* __restrict__ table2, const float* __restrict__ wsum,
    float* __restrict__ o_str) {
    int bid = blockIdx.x, t = threadIdx.x;
    int v0 = bid * 64;
    __shared__ float Wt[64 * 16];       // [v_loc][b]
    {
        int wb = t >> 4, x = t & 15;
        float4 wv = *(const float4*)(wsum + (size_t)wb * Vdim + v0 + x * 4);
        Wt[(x * 4 + 0) * 16 + wb] = wv.x;
        Wt[(x * 4 + 1) * 16 + wb] = wv.y;
        Wt[(x * 4 + 2) * 16 + wb] = wv.z;
        Wt[(x * 4 + 3) * 16 + wb] = wv.w;
    }
    __syncthreads();
    int d4 = t & 63, bh = t >> 6;
    float4 a0 = make_float4(0.f,0.f,0.f,0.f), a1 = a0, a2 = a0, a3 = a0;
#pragma unroll 4
    for (int r = 0; r < 64; ++r) {
        float4 c = *(const float4*)(table2 + (size_t)(v0 + r) * Ddim + d4 * 4);
        float4 wv = *(const float4*)(Wt + r * 16 + bh * 4);
        a0.x += wv.x*c.x; a0.y += wv.x*c.y; a0.z += wv.x*c.z; a0.w += wv.x*c.w;
        a1.x += wv.y*c.x; a1.y += wv.y*c.y; a1.z += wv.y*c.z; a1.w += wv.y*c.w;
        a2.x += wv.z*c.x; a2.y += wv.z*c.y; a2.z += wv.z*c.z; a2.w += wv.z*c.w;
        a3.x += wv.w*c.x; a3.y += wv.w*c.y; a3.z += wv.w*c.z; a3.w += wv.w*c.w;
    }
    float* op = o_str + ((size_t)bid * Bdim + bh * 4) * Ddim + d4 * 4;
    *(float4*)(op + 0 * Ddim) = a0;
    *(float4*)(op + 1 * Ddim) = a1;
    *(float4*)(op + 2 * Ddim) = a2;
    *(float4*)(op + 3 * Ddim) = a3;
}

// ---------------------------------------------------------------------------
// K3b: o[b][d] = o_win[b][d] + sum_s o_str[s][b][d]   grid 64 = 16 b x 4 dq
// ---------------------------------------------------------------------------
__global__ __launch_bounds__(256) void oreduce_kernel(
    const float* __restrict__ o_str, const float* __restrict__ o_win,
    float* __restrict__ o) {
    int bid = blockIdx.x, t = threadIdx.x;
    int b = bid >> 2, dq = bid & 3;
    int d = dq * 64 + (t & 63), sg = t >> 6;
    float a = 0.f;
    for (int s = sg; s < NVBLK; s += 4)
        a += o_str[((size_t)s * Bdim + b) * Ddim + d];
    __shared__ float sh[256];
    sh[t] = a;
    __syncthreads();
    if (t < 64)
        o[b * Ddim + dq * 64 + t] = sh[t] + sh[t + 64] + sh[t + 128] + sh[t + 192]
                                    + o_win[b * Ddim + dq * 64 + t];
}

// ---------------------------------------------------------------------------
// K4: u_out = u_in + o, optional gate (Tg matvec). grid 16 x 256
// ---------------------------------------------------------------------------
__global__ __launch_bounds__(256) void update_kernel(
    const float* __restrict__ u_in, const float* __restrict__ o, int use_gate,
    const float* __restrict__ W, const float* __restrict__ bias,
    const float* __restrict__ prevu, float* __restrict__ u_out) {
    int b = blockIdx.x, i = threadIdx.x;
    __shared__ float sh[Ddim];
    float uk = u_in[(size_t)b * Ddim + i] + o[b * Ddim + i];
    if (!use_gate) { u_out[(size_t)b * Ddim + i] = uk; return; }
    sh[i] = uk; __syncthreads();
    float s = bias[i];
    const float4* Wr = (const float4*)(W + (size_t)i * Ddim);
    const float4* sh4 = (const float4*)sh;
    for (int j = 0; j < 64; ++j) {
        float4 w = Wr[j], x = sh4[j];
        s += w.x * x.x + w.y * x.y + w.z * x.z + w.w * x.w;
    }
    float g = 1.0f / (1.0f + expf(-s));
    u_out[(size_t)b * Ddim + i] = prevu[(size_t)b * Ddim + i] * g + uk * (1.0f - g);
}

// ---------------------------------------------------------------------------
// start: layer0: u0 = query; else q = relu(FW·prev_u3+b) then gate with Tg[0]
// ---------------------------------------------------------------------------
__global__ __launch_bounds__(256) void start_kernel(
    int layer0, const float* __restrict__ query, const float* __restrict__ FW_w,
    const float* __restrict__ FW_b, const float* __restrict__ Tg_w,
    const float* __restrict__ Tg_b, const float* __restrict__ prev_u,
    float* __restrict__ u0_out) {
    int b = blockIdx.x, i = threadIdx.x;
    __shared__ float sh[Ddim];
    __shared__ float qsh[Ddim];
    if (layer0) { u0_out[(size_t)b * Ddim + i] = query[(size_t)b * Ddim + i]; return; }
    sh[i] = prev_u[(size_t)3 * Bdim * Ddim + b * Ddim + i];
    __syncthreads();
    float s = FW_b[i];
    {
        const float4* Wr = (const float4*)(FW_w + (size_t)i * Ddim);
        const float4* sh4 = (const float4*)sh;
        for (int j = 0; j < 64; ++j) {
            float4 w = Wr[j], x = sh4[j];
            s += w.x * x.x + w.y * x.y + w.z * x.z + w.w * x.w;
        }
    }
    float q = fmaxf(s, 0.f);
    qsh[i] = q;
    __syncthreads();
    float tt = Tg_b[i];
    {
        const float4* Wr = (const float4*)(Tg_w + (size_t)i * Ddim);
        const float4* sh4 = (const float4*)qsh;
        for (int j = 0; j < 64; ++j) {
            float4 w = Wr[j], x = sh4[j];
            tt += w.x * x.x + w.y * x.y + w.z * x.z + w.w * x.w;
        }
    }
    float g = 1.0f / (1.0f + expf(-tt));
    u0_out[(size_t)b * Ddim + i] = prev_u[(size_t)b * Ddim + i] * g + q * (1.0f - g);
}

extern "C" void kernel_launch(void* const* d_in, const int* in_sizes, int n_in,
                              void* d_out, int out_size, void* d_ws, size_t ws_size,
                              hipStream_t stream) {
    const int*   story        = (const int*)d_in[0];
    const int*   kb_len       = (const int*)d_in[1];
    const int*   conv_len     = (const int*)d_in[2];
    const float* query        = (const float*)d_in[3];
    const float* hist         = (const float*)d_in[4];
    const float* query_vector = (const float*)d_in[5];
    const float* gp           = (const float*)d_in[6];
    const float* C_emb        = (const float*)d_in[7];
    const float* Tg_w         = (const float*)d_in[8];
    const float* Tg_b         = (const float*)d_in[9];
    const float* FW_w         = (const float*)d_in[10];
    const float* FW_b         = (const float*)d_in[11];

    float* out        = (float*)d_out;
    float* out_psoft  = out;
    float* out_logits = out + (size_t)Bdim * Mdim;
    float* out_uf     = out + 2 * (size_t)Bdim * Mdim;
    float* out_m      = out + 2 * (size_t)Bdim * Mdim + (size_t)Bdim * Ddim;

    const size_t BV = (size_t)Bdim * Vdim;
    const size_t BD = (size_t)Bdim * Ddim;
    const size_t VD = (size_t)Vdim * Ddim;
    float* ws      = (float*)d_ws;
    float* rd      = ws;                                  // V*16
    float* wsum    = rd + BV;                             // 16*V
    float* hw      = wsum + BV;                           // 16*512
    float* o_win   = hw + (size_t)Bdim * CONVMAX;         // 16*256
    float* o       = o_win + BD;                          // 16*256
    float* pmax    = o + BD;                              // 256
    float* psum    = pmax + 256;                          // 256
    float* logits  = psum + 256;                          // 16*4096
    float* o_str   = logits + (size_t)Bdim * Mdim;        // 625*16*256
    float* uA      = o_str + (size_t)NVBLK * BD;          // 4*B*D
    float* uB      = uA + 4 * BD;                         // 4*B*D

    embed3_kernel<<<Bdim * (Mdim / 4), 256, 0, stream>>>(
        story, kb_len, conv_len, hist, C_emb + 3 * VD, out_m);

    // one attention stage: tables (k, k+1), input u -> writes o
    auto stage = [&](const float* tabA, const float* tabB, const float* u,
                     const float* gpp, float* lgbuf, float* psoftbuf) {
        rowdot_kernel<<<NVBLK + 64, 256, 0, stream>>>(tabA, u, hist, rd, hw, wsum, o_win);
        logit_kernel<<<256, 256, 0, stream>>>(story, kb_len, conv_len, rd, hw, gpp,
                                              lgbuf, pmax, psum);
        scatter_kernel<<<256, 256, 0, stream>>>(story, kb_len, conv_len, lgbuf, pmax,
                                                psum, gpp, hist, wsum, o_win, psoftbuf);
        wsum_sweep_kernel<<<NVBLK, 256, 0, stream>>>(tabB, wsum, o_str);
        oreduce_kernel<<<64, 256, 0, stream>>>(o_str, o_win, o);
    };

    float* cur = uA;
    float* prev = uB;
    for (int layer = 0; layer < 3; ++layer) {
        start_kernel<<<Bdim, Ddim, 0, stream>>>(
            layer == 0 ? 1 : 0, query, FW_w, FW_b, Tg_w, Tg_b, prev, cur);
        for (int hop = 0; hop < 3; ++hop) {
            const float* u = cur + (size_t)hop * BD;
            stage(C_emb + (size_t)hop * VD, C_emb + (size_t)(hop + 1) * VD, u,
                  nullptr, logits, nullptr);
            update_kernel<<<Bdim, Ddim, 0, stream>>>(
                u, o, layer > 0 ? 1 : 0,
                Tg_w + (size_t)(hop + 1) * Ddim * Ddim, Tg_b + (size_t)(hop + 1) * Ddim,
                prev + (size_t)(hop + 1) * BD, cur + (size_t)(hop + 1) * BD);
        }
        float* tmp = cur; cur = prev; prev = tmp;
    }

    for (int h = 0; h < 3; ++h) {
        const float* uf = (h == 0) ? query_vector : out_uf;
        stage(C_emb + (size_t)h * VD, C_emb + (size_t)(h + 1) * VD, uf, gp,
              (h == 2) ? out_logits : logits, (h == 2) ? out_psoft : nullptr);
        update_kernel<<<Bdim, Ddim, 0, stream>>>(
            uf, o, 0, nullptr, nullptr, nullptr, out_uf);
    }
}

// Round 4
// 1752.281 us; speedup vs baseline: 1.5132x; 1.3383x over previous
//
#include <hip/hip_runtime.h>
#include <hip/hip_bf16.h>
#include <math.h>

#define Bdim 16
#define Mdim 4096
#define Ddim 256
#define Vdim 40000
#define CONVMAX 512
#define RD_BLOCKS 2500     // 16 rows per block
#define SW_BLOCKS 625      // 64 rows per block

// ---------------------------------------------------------------------------
// embed3: out_m[b,m,:] = sum_t C3[story[b,m,t],:] (+ history window)
// ---------------------------------------------------------------------------
__global__ __launch_bounds__(256) void embed3_kernel(
    const int* __restrict__ story, const int* __restrict__ kb_len,
    const int* __restrict__ conv_len, const float* __restrict__ hist,
    const float* __restrict__ tab, float* __restrict__ outm) {
    int bid = blockIdx.x;
    int b   = bid / (Mdim / 4);
    int mc  = bid % (Mdim / 4);
    int tid = threadIdx.x;
    int m   = mc * 4 + (tid >> 6);
    int lane = tid & 63;
    int d4  = lane * 4;

    const int* st = story + ((size_t)b * Mdim + m) * 4;
    float4 acc = make_float4(0.f, 0.f, 0.f, 0.f);
#pragma unroll
    for (int t = 0; t < 4; ++t) {
        const float4 v = *(const float4*)(tab + (size_t)st[t] * Ddim + d4);
        acc.x += v.x; acc.y += v.y; acc.z += v.z; acc.w += v.w;
    }
    int kb = kb_len[b], cl = conv_len[b];
    if (m >= kb && m < kb + cl) {
        const float4 h = *(const float4*)(hist + ((size_t)b * CONVMAX + (m - kb)) * Ddim + d4);
        acc.x += h.x; acc.y += h.y; acc.z += h.z; acc.w += h.w;
    }
    *(float4*)(outm + ((size_t)b * Mdim + m) * Ddim + d4) = acc;
}

// ---------------------------------------------------------------------------
// K1 rowdot: rd[v][b] = C[v]·u[b].  Wave = 1 row per pass (lane = f4 of d),
// u in registers (16 f4/lane), 6-step shfl_xor reduction, lane0 stores 16 b.
// Tail blocks: hw[b][j] = hist[b][j]·u[b]; zero o_win.
// Main blocks also zero their wsum slice.
// ---------------------------------------------------------------------------
__global__ __launch_bounds__(256) void rowdot_kernel(
    const float* __restrict__ table, const float* __restrict__ u,
    const float* __restrict__ histin, float* __restrict__ rd,
    float* __restrict__ hw, float* __restrict__ wsum, float* __restrict__ o_win) {
    int bid = blockIdx.x, t = threadIdx.x;

    if (bid >= RD_BLOCKS) {
        int xb = bid - RD_BLOCKS;          // 0..63
        int b = xb >> 2, jq = xb & 3;
        if (jq == 0) o_win[b * Ddim + t] = 0.f;
        int wid = t >> 6, lane = t & 63;
        const float4 uv = ((const float4*)(u + (size_t)b * Ddim))[lane];
#pragma unroll 4
        for (int rep = 0; rep < 32; ++rep) {
            int j = jq * 128 + wid * 32 + rep;
            const float4 h = ((const float4*)(histin + ((size_t)b * CONVMAX + j) * Ddim))[lane];
            float s = h.x * uv.x + h.y * uv.y + h.z * uv.z + h.w * uv.w;
#pragma unroll
            for (int off = 32; off > 0; off >>= 1) s += __shfl_xor(s, off, 64);
            if (lane == 0) hw[b * CONVMAX + j] = s;
        }
        return;
    }

    int v0 = bid * 16;
    // zero wsum slice: 16 b x 16 v
    wsum[(size_t)(t >> 4) * Vdim + v0 + (t & 15)] = 0.f;

    int lane = t & 63, w = t >> 6;
    float4 ub[16];
#pragma unroll
    for (int b = 0; b < 16; ++b)
        ub[b] = *(const float4*)(u + (size_t)b * Ddim + 4 * lane);

#pragma unroll
    for (int r = 0; r < 4; ++r) {
        int v = v0 + w * 4 + r;
        const float4 c = *(const float4*)(table + (size_t)v * Ddim + 4 * lane);
        float a[16];
#pragma unroll
        for (int b = 0; b < 16; ++b)
            a[b] = c.x * ub[b].x + c.y * ub[b].y + c.z * ub[b].z + c.w * ub[b].w;
#pragma unroll
        for (int off = 1; off < 64; off <<= 1) {
#pragma unroll
            for (int b = 0; b < 16; ++b) a[b] += __shfl_xor(a[b], off, 64);
        }
        if (lane == 0) {
            float* rp = rd + (size_t)v * Bdim;
            *(float4*)(rp + 0)  = make_float4(a[0],  a[1],  a[2],  a[3]);
            *(float4*)(rp + 4)  = make_float4(a[4],  a[5],  a[6],  a[7]);
            *(float4*)(rp + 8)  = make_float4(a[8],  a[9],  a[10], a[11]);
            *(float4*)(rp + 12) = make_float4(a[12], a[13], a[14], a[15]);
        }
    }
}

// ---------------------------------------------------------------------------
// K2 logit: grid 1024 = 16 b x 64 chunks of 64 m; thread = (m_local, token).
// logits[b][m] = sum_tok rd[st][b] + window (+ *gp); per-chunk (max, sumexp).
// ---------------------------------------------------------------------------
__global__ __launch_bounds__(256) void logit_kernel(
    const int* __restrict__ story, const int* __restrict__ kb_len,
    const int* __restrict__ conv_len, const float* __restrict__ rd,
    const float* __restrict__ hw, const float* __restrict__ gp,
    float* __restrict__ logits, float* __restrict__ pmax, float* __restrict__ psum) {
    int bid = blockIdx.x, t = threadIdx.x;
    int b = bid >> 6, mc = bid & 63;
    int tok = t & 3, ml = t >> 2;
    int m = mc * 64 + ml;

    int sidx = story[((size_t)b * Mdim + m) * 4 + tok];
    float s = rd[(size_t)sidx * Bdim + b];
    s += __shfl_xor(s, 1, 64);
    s += __shfl_xor(s, 2, 64);          // all 4 tok lanes hold the token-sum
    int kb = kb_len[b], cl = conv_len[b];
    int j = m - kb;
    if (j >= 0 && j < cl) s += hw[b * CONVMAX + j];
    if (gp) s *= gp[(size_t)b * Mdim + m];
    if (tok == 0) logits[(size_t)b * Mdim + m] = s;

    __shared__ float shm[4], shs[4];
    float mx = s;
#pragma unroll
    for (int off = 4; off < 64; off <<= 1) mx = fmaxf(mx, __shfl_xor(mx, off, 64));
    if ((t & 63) == 0) shm[t >> 6] = mx;
    __syncthreads();
    float bmax = fmaxf(fmaxf(shm[0], shm[1]), fmaxf(shm[2], shm[3]));
    float e = expf(s - bmax);
#pragma unroll
    for (int off = 4; off < 64; off <<= 1) e += __shfl_xor(e, off, 64);
    if ((t & 63) == 0) shs[t >> 6] = e;
    __syncthreads();
    if (t == 0) {
        pmax[bid] = bmax;
        psum[bid] = shs[0] + shs[1] + shs[2] + shs[3];
    }
}

// ---------------------------------------------------------------------------
// K3 scatter: combine 64 chunk partials (lane-parallel), softmax, atomics
// into wsum histogram, window-o fold (overlapping blocks), psoft output.
// ---------------------------------------------------------------------------
__global__ __launch_bounds__(256) void scatter_kernel(
    const int* __restrict__ story, const int* __restrict__ kb_len,
    const int* __restrict__ conv_len, const float* __restrict__ logits,
    const float* __restrict__ pmax, const float* __restrict__ psum,
    const float* __restrict__ gp, const float* __restrict__ histin,
    float* __restrict__ wsum, float* __restrict__ o_win,
    float* __restrict__ out_psoft) {
    int bid = blockIdx.x, t = threadIdx.x;
    int b = bid >> 6, mc = bid & 63;
    int tok = t & 3, ml = t >> 2;
    int m0 = mc * 64, m = m0 + ml;
    int lane = t & 63;

    // combine 64 chunk partials: lane L owns chunk L
    float pm = pmax[b * 64 + lane];
    float mx = pm;
#pragma unroll
    for (int off = 1; off < 64; off <<= 1) mx = fmaxf(mx, __shfl_xor(mx, off, 64));
    float contrib = psum[b * 64 + lane] * expf(pm - mx);
#pragma unroll
    for (int off = 1; off < 64; off <<= 1) contrib += __shfl_xor(contrib, off, 64);
    float rs = 1.0f / contrib;

    float lg = logits[(size_t)b * Mdim + m];
    float p = expf(lg - mx) * rs;
    if (out_psoft && tok == 0) out_psoft[(size_t)b * Mdim + m] = p;
    float w = p;
    if (gp) w *= gp[(size_t)b * Mdim + m];

    int sidx = story[((size_t)b * Mdim + m) * 4 + tok];
    atomicAdd(&wsum[(size_t)b * Vdim + sidx], w);

    // window-o fold for blocks overlapping [kb, kb+cl)
    __shared__ float pw[64];
    if (tok == 0) pw[ml] = w;
    __syncthreads();
    int kb = kb_len[b], cl = conv_len[b];
    int lo = kb > m0 ? kb : m0;
    int hi = (kb + cl) < (m0 + 64) ? (kb + cl) : (m0 + 64);
    if (lo < hi) {
        int d = t;
        float acc = 0.f;
        for (int mm = lo; mm < hi; ++mm)
            acc += pw[mm - m0] * histin[((size_t)b * CONVMAX + (mm - kb)) * Ddim + d];
        atomicAdd(&o_win[b * Ddim + d], acc);
    }
}

// ---------------------------------------------------------------------------
// K4 sweep: o_str[b][bid][d] = sum_{v in 64-row tile} wsum[b][v] * C2[v][d]
// Wave w owns rows w*16..w*16+15 (no cross-wave duplication); lane = f4 of d.
// Per-wave LDS partial quadrants, folded at the end (no atomics).
// ---------------------------------------------------------------------------
__global__ __launch_bounds__(256) void sweep_kernel(
    const float* __restrict__ table2, const float* __restrict__ wsum,
    float* __restrict__ o_str) {
    int bid = blockIdx.x, t = threadIdx.x;
    int v0 = bid * 64;
    __shared__ float Wt[64 * 16];           // [r][b]
    __shared__ float Of[4 * Bdim * Ddim];   // 64 KB: per-wave quadrants
    {
        int b = t >> 4, x = t & 15;
        float4 wv = *(const float4*)(wsum + (size_t)b * Vdim + v0 + x * 4);
        Wt[(x * 4 + 0) * 16 + b] = wv.x;
        Wt[(x * 4 + 1) * 16 + b] = wv.y;
        Wt[(x * 4 + 2) * 16 + b] = wv.z;
        Wt[(x * 4 + 3) * 16 + b] = wv.w;
    }
    __syncthreads();

    int lane = t & 63, w = t >> 6;
    float4 acc[16];
#pragma unroll
    for (int i = 0; i < 16; ++i) acc[i] = make_float4(0.f, 0.f, 0.f, 0.f);

#pragma unroll 4
    for (int rr = 0; rr < 16; ++rr) {
        int r = w * 16 + rr;
        const float4 c = *(const float4*)(table2 + (size_t)(v0 + r) * Ddim + 4 * lane);
        const float* wr = Wt + r * 16;
#pragma unroll
        for (int b = 0; b < 16; ++b) {
            float wb = wr[b];
            acc[b].x += wb * c.x; acc[b].y += wb * c.y;
            acc[b].z += wb * c.z; acc[b].w += wb * c.w;
        }
    }
    // per-wave quadrant write then fold
    float* q = Of + (size_t)w * Bdim * Ddim;
#pragma unroll
    for (int b = 0; b < 16; ++b)
        *(float4*)(q + b * Ddim + 4 * lane) = acc[b];
    __syncthreads();
    // 1024 f4 totals; thread t handles f4 indices t, t+256, t+512, t+768
#pragma unroll
    for (int k = 0; k < 4; ++k) {
        int i = t + k * 256;                 // f4 index over [16 b][64 d4]
        int b = i >> 6, d4 = i & 63;
        float4 s0 = *(const float4*)(Of + (0 * Bdim + b) * Ddim + 4 * d4);
        float4 s1 = *(const float4*)(Of + (1 * Bdim + b) * Ddim + 4 * d4);
        float4 s2 = *(const float4*)(Of + (2 * Bdim + b) * Ddim + 4 * d4);
        float4 s3 = *(const float4*)(Of + (3 * Bdim + b) * Ddim + 4 * d4);
        float4 r = make_float4(s0.x + s1.x + s2.x + s3.x, s0.y + s1.y + s2.y + s3.y,
                               s0.z + s1.z + s2.z + s3.z, s0.w + s1.w + s2.w + s3.w);
        *(float4*)(o_str + ((size_t)b * SW_BLOCKS + bid) * Ddim + 4 * d4) = r;
    }
}

// ---------------------------------------------------------------------------
// K5 oreduce: o[b][d] = o_win[b][d] + sum_s o_str[b][s][d]
// grid 256 = 16 b x 16 d-chunks of 16; thread = (sg 16, di 16)
// ---------------------------------------------------------------------------
__global__ __launch_bounds__(256) void oreduce_kernel(
    const float* __restrict__ o_str, const float* __restrict__ o_win,
    float* __restrict__ o) {
    int bid = blockIdx.x, t = threadIdx.x;
    int b = bid >> 4, dc = bid & 15;
    int sg = t >> 4, di = t & 15;
    float a = 0.f;
    for (int s = sg; s < SW_BLOCKS; s += 16)
        a += o_str[((size_t)b * SW_BLOCKS + s) * Ddim + dc * 16 + di];
    __shared__ float sh[256];
    sh[t] = a;
    __syncthreads();
#pragma unroll
    for (int st = 128; st >= 16; st >>= 1) {
        if (t < st) sh[t] += sh[t + st];
        __syncthreads();
    }
    if (t < 16)
        o[b * Ddim + dc * 16 + t] = sh[t] + o_win[b * Ddim + dc * 16 + t];
}

// ---------------------------------------------------------------------------
// K6 update: u_out = u_in + o, optional gate (Tg matvec)
// ---------------------------------------------------------------------------
__global__ __launch_bounds__(256) void update_kernel(
    const float* __restrict__ u_in, const float* __restrict__ o, int use_gate,
    const float* __restrict__ W, const float* __restrict__ bias,
    const float* __restrict__ prevu, float* __restrict__ u_out) {
    int b = blockIdx.x, i = threadIdx.x;
    __shared__ float sh[Ddim];
    float uk = u_in[(size_t)b * Ddim + i] + o[b * Ddim + i];
    if (!use_gate) { u_out[(size_t)b * Ddim + i] = uk; return; }
    sh[i] = uk; __syncthreads();
    float s = bias[i];
    const float4* Wr = (const float4*)(W + (size_t)i * Ddim);
    const float4* sh4 = (const float4*)sh;
    for (int j = 0; j < 64; ++j) {
        float4 w = Wr[j], x = sh4[j];
        s += w.x * x.x + w.y * x.y + w.z * x.z + w.w * x.w;
    }
    float g = 1.0f / (1.0f + expf(-s));
    u_out[(size_t)b * Ddim + i] = prevu[(size_t)b * Ddim + i] * g + uk * (1.0f - g);
}

// ---------------------------------------------------------------------------
// start: layer0: u0 = query; else q = relu(FW·prev_u3+b) then gate with Tg[0]
// ---------------------------------------------------------------------------
__global__ __launch_bounds__(256) void start_kernel(
    int layer0, const float* __restrict__ query, const float* __restrict__ FW_w,
    const float* __restrict__ FW_b, const float* __restrict__ Tg_w,
    const float* __restrict__ Tg_b, const float* __restrict__ prev_u,
    float* __restrict__ u0_out) {
    int b = blockIdx.x, i = threadIdx.x;
    __shared__ float sh[Ddim];
    __shared__ float qsh[Ddim];
    if (layer0) { u0_out[(size_t)b * Ddim + i] = query[(size_t)b * Ddim + i]; return; }
    sh[i] = prev_u[(size_t)3 * Bdim * Ddim + b * Ddim + i];
    __syncthreads();
    float s = FW_b[i];
    {
        const float4* Wr = (const float4*)(FW_w + (size_t)i * Ddim);
        const float4* sh4 = (const float4*)sh;
        for (int j = 0; j < 64; ++j) {
            float4 w = Wr[j], x = sh4[j];
            s += w.x * x.x + w.y * x.y + w.z * x.z + w.w * x.w;
        }
    }
    float q = fmaxf(s, 0.f);
    qsh[i] = q;
    __syncthreads();
    float tt = Tg_b[i];
    {
        const float4* Wr = (const float4*)(Tg_w + (size_t)i * Ddim);
        const float4* sh4 = (const float4*)qsh;
        for (int j = 0; j < 64; ++j) {
            float4 w = Wr[j], x = sh4[j];
            tt += w.x * x.x + w.y * x.y + w.z * x.z + w.w * x.w;
        }
    }
    float g = 1.0f / (1.0f + expf(-tt));
    u0_out[(size_t)b * Ddim + i] = prev_u[(size_t)b * Ddim + i] * g + q * (1.0f - g);
}

extern "C" void kernel_launch(void* const* d_in, const int* in_sizes, int n_in,
                              void* d_out, int out_size, void* d_ws, size_t ws_size,
                              hipStream_t stream) {
    const int*   story        = (const int*)d_in[0];
    const int*   kb_len       = (const int*)d_in[1];
    const int*   conv_len     = (const int*)d_in[2];
    const float* query        = (const float*)d_in[3];
    const float* hist         = (const float*)d_in[4];
    const float* query_vector = (const float*)d_in[5];
    const float* gp           = (const float*)d_in[6];
    const float* C_emb        = (const float*)d_in[7];
    const float* Tg_w         = (const float*)d_in[8];
    const float* Tg_b         = (const float*)d_in[9];
    const float* FW_w         = (const float*)d_in[10];
    const float* FW_b         = (const float*)d_in[11];

    float* out        = (float*)d_out;
    float* out_psoft  = out;
    float* out_logits = out + (size_t)Bdim * Mdim;
    float* out_uf     = out + 2 * (size_t)Bdim * Mdim;
    float* out_m      = out + 2 * (size_t)Bdim * Mdim + (size_t)Bdim * Ddim;

    const size_t BV = (size_t)Bdim * Vdim;
    const size_t BD = (size_t)Bdim * Ddim;
    const size_t VD = (size_t)Vdim * Ddim;
    float* ws      = (float*)d_ws;
    float* rd      = ws;                                   // V*16
    float* wsum    = rd + BV;                              // 16*V
    float* hw      = wsum + BV;                            // 16*512
    float* o_win   = hw + (size_t)Bdim * CONVMAX;          // 16*256
    float* o       = o_win + BD;                           // 16*256
    float* pmax    = o + BD;                               // 1024
    float* psum    = pmax + 1024;                          // 1024
    float* logits  = psum + 1024;                          // 16*4096
    float* o_str   = logits + (size_t)Bdim * Mdim;         // 16*625*256
    float* uA      = o_str + (size_t)Bdim * SW_BLOCKS * Ddim;
    float* uB      = uA + 4 * BD;

    embed3_kernel<<<Bdim * (Mdim / 4), 256, 0, stream>>>(
        story, kb_len, conv_len, hist, C_emb + 3 * VD, out_m);

    auto stage = [&](const float* tabA, const float* tabB, const float* u,
                     const float* gpp, float* lgbuf, float* psoftbuf) {
        rowdot_kernel<<<RD_BLOCKS + 64, 256, 0, stream>>>(tabA, u, hist, rd, hw, wsum, o_win);
        logit_kernel<<<1024, 256, 0, stream>>>(story, kb_len, conv_len, rd, hw, gpp,
                                               lgbuf, pmax, psum);
        scatter_kernel<<<1024, 256, 0, stream>>>(story, kb_len, conv_len, lgbuf, pmax,
                                                 psum, gpp, hist, wsum, o_win, psoftbuf);
        sweep_kernel<<<SW_BLOCKS, 256, 0, stream>>>(tabB, wsum, o_str);
        oreduce_kernel<<<256, 256, 0, stream>>>(o_str, o_win, o);
    };

    float* cur = uA;
    float* prev = uB;
    for (int layer = 0; layer < 3; ++layer) {
        start_kernel<<<Bdim, Ddim, 0, stream>>>(
            layer == 0 ? 1 : 0, query, FW_w, FW_b, Tg_w, Tg_b, prev, cur);
        for (int hop = 0; hop < 3; ++hop) {
            const float* u = cur + (size_t)hop * BD;
            stage(C_emb + (size_t)hop * VD, C_emb + (size_t)(hop + 1) * VD, u,
                  nullptr, logits, nullptr);
            update_kernel<<<Bdim, Ddim, 0, stream>>>(
                u, o, layer > 0 ? 1 : 0,
                Tg_w + (size_t)(hop + 1) * Ddim * Ddim, Tg_b + (size_t)(hop + 1) * Ddim,
                prev + (size_t)(hop + 1) * BD, cur + (size_t)(hop + 1) * BD);
        }
        float* tmp = cur; cur = prev; prev = tmp;
    }

    for (int h = 0; h < 3; ++h) {
        const float* uf = (h == 0) ? query_vector : out_uf;
        stage(C_emb + (size_t)h * VD, C_emb + (size_t)(h + 1) * VD, uf, gp,
              (h == 2) ? out_logits : logits, (h == 2) ? out_psoft : nullptr);
        update_kernel<<<Bdim, Ddim, 0, stream>>>(
            uf, o, 0, nullptr, nullptr, nullptr, out_uf);
    }
}